// Round 12
// baseline (180.355 us; speedup 1.0000x reference)
//
#include <hip/hip_runtime.h>
#include <math.h>

#define PADC 1
#define CIN  64
#define COUT 128
#define IH   64
#define IW   64
#define NB   16
#define OYX  129
#define OXP  136            // padded y_bf row (16B-aligned rows)
#define NOFF 18
#define SPO  (OYX * OYX)   // 16641
#define BNEPS 1e-5f
#define NBLK_CT (NB * 65)  // 1040 paired convT blocks

typedef __attribute__((ext_vector_type(8))) short bf16x8;
typedef __attribute__((ext_vector_type(4))) float f32x4;

static __device__ __forceinline__ unsigned short f2bf(float f) {
    unsigned int b = __float_as_uint(f);
    unsigned int r = (b + 0x7FFFu + ((b >> 16) & 1u)) >> 16;   // RNE
    return (unsigned short)r;
}
static __device__ __forceinline__ float bf2f(unsigned short u) {
    return __uint_as_float((unsigned int)u << 16);
}

// ---------------- merged pre-pass: blocks [0,1024) = x transpose, rest = weight prep ----------------
__global__ __launch_bounds__(256) void k_pre(
    const float* __restrict__ x, const float* __restrict__ w_def,
    const float* __restrict__ w_up, const float* __restrict__ w_off,
    unsigned short* __restrict__ xt, unsigned short* __restrict__ WDF,
    unsigned short* __restrict__ WB, unsigned short* __restrict__ WOF)
{
    __shared__ unsigned short t[64][66];
    const int tid = threadIdx.x;
    if (blockIdx.x < 1024) {
        const int h = blockIdx.x & 63, b = blockIdx.x >> 6;
        const int w = tid & 63, cq = tid >> 6;
        #pragma unroll
        for (int p = 0; p < 16; ++p) {
            const int c = p * 4 + cq;
            t[w][c] = f2bf(x[((size_t)((b * 64 + c) * 64) + h) * 64 + w]);
        }
        __syncthreads();
        const int w2 = tid >> 2, q = tid & 3;
        unsigned int pk[8];
        #pragma unroll
        for (int m = 0; m < 8; ++m)
            pk[m] = (unsigned int)t[w2][q * 16 + 2 * m] | ((unsigned int)t[w2][q * 16 + 2 * m + 1] << 16);
        uint4* dst = (uint4*)(xt + ((size_t)((b * 64 + h) * 64) + w2) * 64 + q * 16);
        dst[0] = uint4{pk[0], pk[1], pk[2], pk[3]};
        dst[1] = uint4{pk[4], pk[5], pk[6], pk[7]};
        return;
    }
    int idx = (blockIdx.x - 1024) * 256 + tid;
    if (idx < 73728) {
        const int j = idx & 7;
        const int n = (idx >> 3) & 127;
        const int g = idx >> 10;            // 0..71 = kk*8 + ks*4 + kg
        const int kg = g & 3, ks = (g >> 2) & 1, kk = g >> 3;
        const int c = ks * 32 + kg * 8 + j;
        WDF[idx] = f2bf(w_def[(n * CIN + c) * 9 + kk]);
    }
    const int i2 = idx - 73728;
    if (i2 >= 0 && i2 < 147456) {
        const int j = i2 & 7;
        const int n = (i2 >> 3) & 127;
        int ky, kx, ci;
        if (i2 < 65536) {
            const int k = (i2 >> 10) * 8 + j;            // 0..511
            ky = (k >> 8) ? 0 : 2;
            kx = ((k >> 7) & 1) ? 0 : 2;
            ci = k & 127;
        } else if (i2 < 98304) {
            const int k = ((i2 - 65536) >> 10) * 8 + j;  // 0..255
            ky = 1;
            kx = (k >> 7) ? 0 : 2;
            ci = k & 127;
        } else if (i2 < 131072) {
            const int k = ((i2 - 98304) >> 10) * 8 + j;  // 0..255
            ky = (k >> 7) ? 0 : 2;
            kx = 1;
            ci = k & 127;
        } else {
            const int k = ((i2 - 131072) >> 10) * 8 + j; // 0..127
            ky = 1; kx = 1;
            ci = k & 127;
        }
        WB[i2] = f2bf(w_up[((ci * COUT + n) * 3 + ky) * 3 + kx]);
    }
    const int i3 = idx - 221184;
    if (i3 >= 0 && i3 < 18432) {
        const int j = i3 & 7;
        const int n = (i3 >> 3) & 31;
        const int g = i3 >> 8;              // 0..71 = s*4 + kg
        const int kg = g & 3, s = g >> 2;
        const int c  = (s & 1) * 32 + kg * 8 + j;
        const int kk = s >> 1;
        const int ki = kk / 3, kj = kk - 3 * ki;
        WOF[i3] = (n < NOFF) ? f2bf(w_off[((n * CIN + c) * 3 + ki) * 3 + kj]) : (unsigned short)0;
    }
}

// ---------------- offset conv via MFMA, 1 wave per (b, h, quarter) ----------------
// Stores pixel-interleaved: offs2[b][h][w][oc], oc in [0,18)
__global__ __launch_bounds__(64, 4) void k_offset_mfma(
    const unsigned short* __restrict__ xt, const unsigned short* __restrict__ WOF,
    const float* __restrict__ b_off, float* __restrict__ offs2)
{
    const int l  = threadIdx.x;
    const int ml = l & 15;
    const int kg = l >> 4;
    const int q  = blockIdx.x & 3;
    const int h  = (blockIdx.x >> 2) & 63;
    const int b  = blockIdx.x >> 8;
    const int w  = q * 16 + ml;
    const unsigned short* xb = xt + (size_t)b * (IH * IW * CIN);

    const f32x4 fz = {0.f, 0.f, 0.f, 0.f};
    f32x4 acc0 = fz, acc1 = fz;

    #pragma unroll 1
    for (int s = 0; s < 18; ++s) {
        const int kk = s >> 1;
        const int ki = kk / 3, kj = kk - 3 * ki;
        const int c0 = (s & 1) * 32 + kg * 8;
        const int yy = h - PADC + ki;
        const int xx = w - PADC + kj;
        const bf16x8 b0 = *(const bf16x8*)(WOF + (size_t)(((s * 4 + kg) * 32 + ml) * 8));
        const bf16x8 b1 = *(const bf16x8*)(WOF + (size_t)(((s * 4 + kg) * 32 + 16 + ml) * 8));
        bf16x8 a = {0, 0, 0, 0, 0, 0, 0, 0};
        if (yy >= 0 && yy < IH && xx >= 0 && xx < IW)
            a = *(const bf16x8*)(xb + (size_t)((yy * IW + xx) * CIN) + c0);
        acc0 = __builtin_amdgcn_mfma_f32_16x16x32_bf16(a, b0, acc0, 0, 0, 0);
        acc1 = __builtin_amdgcn_mfma_f32_16x16x32_bf16(a, b1, acc1, 0, 0, 0);
    }
    // D: row = kg*4 + j (pixel within quarter), col = nt*16 + ml (oc)
    #pragma unroll
    for (int nt = 0; nt < 2; ++nt) {
        const int oc = nt * 16 + ml;
        if (oc < NOFF) {
            const float bias = b_off[oc];
            const f32x4 av = nt ? acc1 : acc0;
            #pragma unroll
            for (int j = 0; j < 4; ++j) {
                const int wd = q * 16 + kg * 4 + j;
                offs2[((size_t)((b * IH + h) * IW) + wd) * NOFF + oc] = av[j] + bias;
            }
        }
    }
}

// ---------------- deformable conv via MFMA, block = (b, h), 4 waves = 4 quarters ----------------
// WDF staged per-kk in LDS (16 KB slice, double-buffered, 1 barrier/kk) and shared
// by all 4 waves: cuts WDF L2 traffic 4x and converts B-frag loads to conflict-free
// ds_read_b128. Global->reg->LDS staging overlaps loads with compute.
__global__ __launch_bounds__(256, 4) void k_deform_mfma(
    const unsigned short* __restrict__ xt, const float* __restrict__ offs2,
    const unsigned short* __restrict__ WDF, const float* __restrict__ b_def,
    unsigned short* __restrict__ feats_bf)
{
    __shared__ __align__(16) unsigned short wlds[2][8192];   // 2 x 16 KB WDF slices

    const int tid = threadIdx.x;
    const int q   = tid >> 6;        // wave = quarter
    const int l   = tid & 63;
    const int ml  = l & 15;
    const int kg  = l >> 4;
    const int h   = blockIdx.x & 63;
    const int b   = blockIdx.x >> 6;
    const int w   = q * 16 + ml;

    const unsigned short* xb = xt + (size_t)b * (IH * IW * CIN);

    // prologue: stage slice 0 directly, preload slice 1 into regs
    uint4 st[4];
    {
        const uint4* s0 = (const uint4*)(WDF);
        #pragma unroll
        for (int i = 0; i < 4; ++i) ((uint4*)wlds[0])[tid + i * 256] = s0[tid + i * 256];
        const uint4* s1 = (const uint4*)(WDF + 8192);
        #pragma unroll
        for (int i = 0; i < 4; ++i) st[i] = s1[tid + i * 256];
    }

    // preload all 9 offset pairs (static indices -> registers)
    float2 dd[9];
    {
        const float* op = offs2 + ((size_t)((b * IH + h) * IW) + w) * NOFF;
        #pragma unroll
        for (int kk = 0; kk < 9; ++kk)
            dd[kk] = *(const float2*)(op + 2 * kk);
    }

    const f32x4 fz = {0.f, 0.f, 0.f, 0.f};
    f32x4 acc[8];
    #pragma unroll
    for (int nt = 0; nt < 8; ++nt) acc[nt] = fz;

    __syncthreads();   // slice 0 visible

    #pragma unroll
    for (int kk = 0; kk < 9; ++kk) {
        const int cur = kk & 1;
        const int ki = kk / 3, kj = kk - 3 * ki;   // compile-time
        const float py = (float)(h - PADC + ki) + dd[kk].x;
        const float px = (float)(w - PADC + kj) + dd[kk].y;
        const float y0f = floorf(py), x0f = floorf(px);
        const float ly = py - y0f, lx = px - x0f;
        const int y0 = (int)y0f, x0 = (int)x0f;
        const float wy[2] = {1.f - ly, ly};
        const float wx[2] = {1.f - lx, lx};
        int   cidx[4];
        float cwgt[4];
        #pragma unroll
        for (int cy = 0; cy < 2; ++cy)
            #pragma unroll
            for (int cx = 0; cx < 2; ++cx) {
                const int yy = y0 + cy, xx = x0 + cx;
                const bool v = (yy >= 0) & (yy < IH) & (xx >= 0) & (xx < IW);
                cidx[cy * 2 + cx] = v ? ((yy * IW + xx) * CIN) : 0;   // branchless
                cwgt[cy * 2 + cx] = v ? (wy[cy] * wx[cx]) : 0.f;
            }
        #pragma unroll
        for (int ks = 0; ks < 2; ++ks) {
            const int c0 = ks * 32 + kg * 8;
            uint4 cv[4];
            #pragma unroll
            for (int cp = 0; cp < 4; ++cp)
                cv[cp] = *(const uint4*)(xb + cidx[cp] + c0);
            float sf[8] = {0.f, 0.f, 0.f, 0.f, 0.f, 0.f, 0.f, 0.f};
            #pragma unroll
            for (int cp = 0; cp < 4; ++cp) {
                const float wg = cwgt[cp];
                const unsigned int u0 = cv[cp].x, u1 = cv[cp].y, u2 = cv[cp].z, u3 = cv[cp].w;
                sf[0] += wg * __uint_as_float(u0 << 16);
                sf[1] += wg * __uint_as_float(u0 & 0xFFFF0000u);
                sf[2] += wg * __uint_as_float(u1 << 16);
                sf[3] += wg * __uint_as_float(u1 & 0xFFFF0000u);
                sf[4] += wg * __uint_as_float(u2 << 16);
                sf[5] += wg * __uint_as_float(u2 & 0xFFFF0000u);
                sf[6] += wg * __uint_as_float(u3 << 16);
                sf[7] += wg * __uint_as_float(u3 & 0xFFFF0000u);
            }
            union { unsigned short us[8]; bf16x8 v; } pa;
            #pragma unroll
            for (int j = 0; j < 8; ++j) pa.us[j] = f2bf(sf[j]);
            // B-fragments from LDS (conflict-free: 8 consecutive lanes -> 8 consecutive granules)
            #pragma unroll
            for (int half = 0; half < 2; ++half) {
                bf16x8 bfr[4];
                #pragma unroll
                for (int nn = 0; nn < 4; ++nn)
                    bfr[nn] = *(const bf16x8*)(&wlds[cur][(((ks * 4 + kg) * 128) + (half * 4 + nn) * 16 + ml) * 8]);
                #pragma unroll
                for (int nn = 0; nn < 4; ++nn)
                    acc[half * 4 + nn] = __builtin_amdgcn_mfma_f32_16x16x32_bf16(pa.v, bfr[nn], acc[half * 4 + nn], 0, 0, 0);
            }
        }
        // stage next slice: write st (slice kk+1) to other buffer, then preload slice kk+2
        if (kk < 8) {
            #pragma unroll
            for (int i = 0; i < 4; ++i) ((uint4*)wlds[1 - cur])[tid + i * 256] = st[i];
            if (kk < 7) {
                const uint4* sn = (const uint4*)(WDF + (size_t)(kk + 2) * 8192);
                #pragma unroll
                for (int i = 0; i < 4; ++i) st[i] = sn[tid + i * 256];
            }
            __syncthreads();
        }
    }

    // epilogue: D row = kg*4 + j (pixel), col = nt*16 + ml (channel o)
    #pragma unroll
    for (int nt = 0; nt < 8; ++nt) {
        const int o = nt * 16 + ml;
        const float bias = b_def[o];
        #pragma unroll
        for (int j = 0; j < 4; ++j) {
            const int wd = q * 16 + kg * 4 + j;
            feats_bf[((size_t)((b * IH + h) * IW) + wd) * COUT + o] = f2bf(acc[nt][j] + bias);
        }
    }
}

// ---------------- convT via MFMA: paired oy rows, slab-free epilogue ----------------
__global__ __launch_bounds__(256) void k_convT_mfma(
    const unsigned short* __restrict__ feats_bf, const unsigned short* __restrict__ WB,
    unsigned short* __restrict__ y_bf, float* __restrict__ partials)
{
    __shared__ __align__(16) char smem[33792];   // 2 slots x 16896

    const int tid = threadIdx.x;
    const int l   = tid & 63;
    const int wv  = tid >> 6;
    const int ml  = l & 15;
    const int kg  = l >> 4;
    const int blk = blockIdx.x;
    const int t   = blk % 65;
    const int b   = blk / 65;

    for (int r = 0; r < 2; ++r) {
        char* dstbase = smem + r * 16896;
        const int iy = t - 1 + r;
        if (iy < 0 || iy > 63) {
            for (int i = tid; i < 1056; i += 256)
                *(uint4*)(dstbase + i * 16) = uint4{0, 0, 0, 0};
        } else {
            const unsigned short* src = feats_bf + (size_t)(b * IH + iy) * (IW * COUT);
            for (int i = tid; i < 1024; i += 256) {
                const uint4 v = *(const uint4*)(src + i * 8);
                const int G = 16 + i;
                const int phys = G ^ ((G >> 4) & 7);
                *(uint4*)(dstbase + phys * 16) = v;
            }
            if (tid < 32) {
                const int G = (tid < 16) ? tid : (1024 + tid);
                const int phys = G ^ ((G >> 4) & 7);
                *(uint4*)(dstbase + phys * 16) = uint4{0, 0, 0, 0};
            }
        }
    }
    __syncthreads();

    const int n0 = wv * 32;
    const f32x4 fz = {0.f, 0.f, 0.f, 0.f};
    float sacc[2] = {0.f, 0.f}, qacc[2] = {0.f, 0.f};

    #pragma unroll 1
    for (int p = 0; p < 2; ++p) {                 // p=0: oy=2t, p=1: oy=2t+1
        if (p == 1 && t == 64) break;
        const int oy = 2 * t + p;
        const unsigned short* segG0 = WB + (p ? 65536 : 0);
        const unsigned short* segG1 = WB + (p ? 131072 : 98304);
        const int nK0 = p ? 8 : 16;
        const int nK1 = p ? 4 : 8;

        f32x4 acc0[5][2], acc1[4][2];
        #pragma unroll
        for (int m = 0; m < 5; ++m) { acc0[m][0] = fz; acc0[m][1] = fz; }
        #pragma unroll
        for (int m = 0; m < 4; ++m) { acc1[m][0] = fz; acc1[m][1] = fz; }

        for (int ks = 0; ks < nK0; ++ks) {
            const int kk   = ks * 32 + kg * 8;
            const int slot = p ? 1 : (kk >> 8);
            const int kb   = (kk & 255) >> 3;
            const bf16x8 b0 = *(const bf16x8*)(segG0 + ((ks * 4 + kg) * 128 + n0 + ml) * 8);
            const bf16x8 b1 = *(const bf16x8*)(segG0 + ((ks * 4 + kg) * 128 + n0 + 16 + ml) * 8);
            #pragma unroll
            for (int mt = 0; mt < 5; ++mt) {
                int tx = mt * 16 + ml; if (tx > 64) tx = 64;
                const int G = tx * 16 + kb;
                const int phys = G ^ ((G >> 4) & 7);
                const bf16x8 a = *(const bf16x8*)(smem + slot * 16896 + phys * 16);
                acc0[mt][0] = __builtin_amdgcn_mfma_f32_16x16x32_bf16(a, b0, acc0[mt][0], 0, 0, 0);
                acc0[mt][1] = __builtin_amdgcn_mfma_f32_16x16x32_bf16(a, b1, acc0[mt][1], 0, 0, 0);
            }
        }
        for (int ks = 0; ks < nK1; ++ks) {
            const int kk   = ks * 32 + kg * 8;
            const int slot = p ? 1 : (kk >> 7);
            const int kb   = (kk & 127) >> 3;
            const bf16x8 b0 = *(const bf16x8*)(segG1 + ((ks * 4 + kg) * 128 + n0 + ml) * 8);
            const bf16x8 b1 = *(const bf16x8*)(segG1 + ((ks * 4 + kg) * 128 + n0 + 16 + ml) * 8);
            #pragma unroll
            for (int mt = 0; mt < 4; ++mt) {
                const int tx = mt * 16 + ml;
                const int G = 16 + tx * 16 + kb;
                const int phys = G ^ ((G >> 4) & 7);
                const bf16x8 a = *(const bf16x8*)(smem + slot * 16896 + phys * 16);
                acc1[mt][0] = __builtin_amdgcn_mfma_f32_16x16x32_bf16(a, b0, acc1[mt][0], 0, 0, 0);
                acc1[mt][1] = __builtin_amdgcn_mfma_f32_16x16x32_bf16(a, b1, acc1[mt][1], 0, 0, 0);
            }
        }

        #pragma unroll
        for (int nt = 0; nt < 2; ++nt) {
            const int co = n0 + nt * 16 + ml;
            unsigned int* drow32 = (unsigned int*)(y_bf + ((size_t)(b * COUT + co) * OYX + oy) * OXP);
            #pragma unroll
            for (int mt = 0; mt < 4; ++mt) {
                unsigned int pk[4];
                #pragma unroll
                for (int j = 0; j < 4; ++j) {
                    const float ve = acc0[mt][nt][j];
                    const float vo = acc1[mt][nt][j];
                    pk[j] = (unsigned int)f2bf(ve) | ((unsigned int)f2bf(vo) << 16);
                    sacc[nt] += ve + vo;
                    qacc[nt] += ve * ve + vo * vo;
                }
                *(uint4*)(drow32 + mt * 16 + kg * 4) = uint4{pk[0], pk[1], pk[2], pk[3]};
            }
            if (kg == 0) {
                const float ve = acc0[4][nt][0];
                drow32[64] = (unsigned int)f2bf(ve);
                sacc[nt] += ve;
                qacc[nt] += ve * ve;
            }
        }
    }

    #pragma unroll
    for (int nt = 0; nt < 2; ++nt) {
        float ss = sacc[nt], qq = qacc[nt];
        ss += __shfl_xor(ss, 16, 64); qq += __shfl_xor(qq, 16, 64);
        ss += __shfl_xor(ss, 32, 64); qq += __shfl_xor(qq, 32, 64);
        if (kg == 0) {
            float* pp = partials + ((size_t)blk * COUT + n0 + nt * 16 + ml) * 2;
            pp[0] = ss; pp[1] = qq;
        }
    }
}

// ---------------- BN finalize: reduce per-block partials ----------------
__global__ __launch_bounds__(256) void k_bn_final(const float* __restrict__ partials,
                                                  float* __restrict__ stats)
{
    const int c = blockIdx.x;      // 128
    const int tid = threadIdx.x;
    float s = 0.f, q = 0.f;
    for (int i = tid; i < NBLK_CT; i += 256) {
        const float* pp = partials + ((size_t)i * COUT + c) * 2;
        s += pp[0]; q += pp[1];
    }
    __shared__ float rs[256], rq[256];
    rs[tid] = s; rq[tid] = q;
    __syncthreads();
    for (int off = 128; off > 0; off >>= 1) {
        if (tid < off) { rs[tid] += rs[tid + off]; rq[tid] += rq[tid + off]; }
        __syncthreads();
    }
    if (tid == 0) {
        const float n = (float)(NB * SPO);
        const float mean = rs[0] / n;
        const float var  = rq[0] / n - mean * mean;
        stats[c] = mean;
        stats[COUT + c] = rsqrtf(var + BNEPS);
    }
}

// ---------------- BN apply + ReLU: 8-wide bf16 read (padded rows), f32 write ----------------
__global__ __launch_bounds__(256) void k_bn_apply(
    const unsigned short* __restrict__ y_bf, float* __restrict__ y,
    const float* __restrict__ stats,
    const float* __restrict__ gamma, const float* __restrict__ beta)
{
    const int v = blockIdx.x * 256 + threadIdx.x;   // exact: 264192*17 = 4,491,264
    const int rid = v / 17;
    const int c   = v - rid * 17;
    const int co  = (rid / OYX) & (COUT - 1);
    const float mean = stats[co], rstd = stats[COUT + co];
    const float ga = gamma[co], be = beta[co];
    const int ox0 = c * 8;

    const uint4 u = *(const uint4*)(y_bf + (size_t)rid * OXP + ox0);
    const unsigned int uu[4] = {u.x, u.y, u.z, u.w};
    float* dst = y + (size_t)rid * OYX + ox0;
    const int nv = (c < 16) ? 8 : 1;
    #pragma unroll
    for (int m = 0; m < 4; ++m) {
        float v0 = bf2f((unsigned short)(uu[m] & 0xFFFFu));
        float v1 = bf2f((unsigned short)(uu[m] >> 16));
        v0 = fmaxf((v0 - mean) * rstd * ga + be, 0.f);
        v1 = fmaxf((v1 - mean) * rstd * ga + be, 0.f);
        if (2 * m < nv)     dst[2 * m]     = v0;
        if (2 * m + 1 < nv) dst[2 * m + 1] = v1;
    }
}

extern "C" void kernel_launch(void* const* d_in, const int* in_sizes, int n_in,
                              void* d_out, int out_size, void* d_ws, size_t ws_size,
                              hipStream_t stream)
{
    const float* x     = (const float*)d_in[0];
    const float* w_off = (const float*)d_in[1];
    const float* b_off = (const float*)d_in[2];
    const float* w_def = (const float*)d_in[3];
    const float* b_def = (const float*)d_in[4];
    const float* w_up  = (const float*)d_in[5];
    const float* b_up  = (const float*)d_in[6];  (void)b_up;  // cancels in BN
    const float* gamma = (const float*)d_in[7];
    const float* beta  = (const float*)d_in[8];
    float* y = (float*)d_out;

    float* ws       = (float*)d_ws;
    float* stats    = ws;                     //       256 f32
    float* partials = stats + 256;            //   266,240 f32 (1040*128*2)
    float* offs2    = partials + 528384;      // 1,179,648 f32 ([b][h][w][18])
    unsigned short* xt       = (unsigned short*)(offs2 + 1179648);    //  4,194,304 bf16
    unsigned short* WDF      = xt + 4194304;                          //     73,728 bf16
    unsigned short* feats_bf = WDF + 73728;                           //  8,388,608 bf16
    unsigned short* WB       = feats_bf + 8388608;                    //    147,456 bf16
    unsigned short* WOF      = WB + 147456;                           //     18,432 bf16
    unsigned short* y_bf     = WOF + 18432;                           // 35,930,112 bf16 (padded rows)

    k_pre          <<<dim3(1960),   dim3(256), 0, stream>>>(x, w_def, w_up, w_off, xt, WDF, WB, WOF);
    k_offset_mfma  <<<dim3(4096),   dim3(64),  0, stream>>>(xt, WOF, b_off, offs2);
    k_deform_mfma  <<<dim3(1024),   dim3(256), 0, stream>>>(xt, offs2, WDF, b_def, feats_bf);
    k_convT_mfma   <<<dim3(NBLK_CT),dim3(256), 0, stream>>>(feats_bf, WB, y_bf, partials);
    k_bn_final     <<<dim3(128),    dim3(256), 0, stream>>>(partials, stats);
    k_bn_apply     <<<dim3(17544),  dim3(256), 0, stream>>>(y_bf, y, stats, gamma, beta);
}

// Round 13
// 161.033 us; speedup vs baseline: 1.1200x; 1.1200x over previous
//
#include <hip/hip_runtime.h>
#include <math.h>

#define PADC 1
#define CIN  64
#define COUT 128
#define IH   64
#define IW   64
#define NB   16
#define OYX  129
#define OXP  136            // padded y_bf row (16B-aligned rows)
#define NOFF 18
#define SPO  (OYX * OYX)   // 16641
#define BNEPS 1e-5f
#define NBLK_CT (NB * 65)  // 1040 paired convT blocks

typedef __attribute__((ext_vector_type(8))) short bf16x8;
typedef __attribute__((ext_vector_type(4))) float f32x4;

static __device__ __forceinline__ unsigned short f2bf(float f) {
    unsigned int b = __float_as_uint(f);
    unsigned int r = (b + 0x7FFFu + ((b >> 16) & 1u)) >> 16;   // RNE
    return (unsigned short)r;
}
static __device__ __forceinline__ float bf2f(unsigned short u) {
    return __uint_as_float((unsigned int)u << 16);
}

// ---------------- merged pre-pass: blocks [0,1024) = x transpose, rest = weight prep ----------------
__global__ __launch_bounds__(256) void k_pre(
    const float* __restrict__ x, const float* __restrict__ w_def,
    const float* __restrict__ w_up, const float* __restrict__ w_off,
    unsigned short* __restrict__ xt, unsigned short* __restrict__ WDF,
    unsigned short* __restrict__ WB, unsigned short* __restrict__ WOF)
{
    __shared__ unsigned short t[64][66];
    const int tid = threadIdx.x;
    if (blockIdx.x < 1024) {
        const int h = blockIdx.x & 63, b = blockIdx.x >> 6;
        const int w = tid & 63, cq = tid >> 6;
        #pragma unroll
        for (int p = 0; p < 16; ++p) {
            const int c = p * 4 + cq;
            t[w][c] = f2bf(x[((size_t)((b * 64 + c) * 64) + h) * 64 + w]);
        }
        __syncthreads();
        const int w2 = tid >> 2, q = tid & 3;
        unsigned int pk[8];
        #pragma unroll
        for (int m = 0; m < 8; ++m)
            pk[m] = (unsigned int)t[w2][q * 16 + 2 * m] | ((unsigned int)t[w2][q * 16 + 2 * m + 1] << 16);
        uint4* dst = (uint4*)(xt + ((size_t)((b * 64 + h) * 64) + w2) * 64 + q * 16);
        dst[0] = uint4{pk[0], pk[1], pk[2], pk[3]};
        dst[1] = uint4{pk[4], pk[5], pk[6], pk[7]};
        return;
    }
    int idx = (blockIdx.x - 1024) * 256 + tid;
    if (idx < 73728) {
        const int j = idx & 7;
        const int n = (idx >> 3) & 127;
        const int g = idx >> 10;            // 0..71 = kk*8 + ks*4 + kg
        const int kg = g & 3, ks = (g >> 2) & 1, kk = g >> 3;
        const int c = ks * 32 + kg * 8 + j;
        WDF[idx] = f2bf(w_def[(n * CIN + c) * 9 + kk]);
    }
    const int i2 = idx - 73728;
    if (i2 >= 0 && i2 < 147456) {
        const int j = i2 & 7;
        const int n = (i2 >> 3) & 127;
        int ky, kx, ci;
        if (i2 < 65536) {
            const int k = (i2 >> 10) * 8 + j;            // 0..511
            ky = (k >> 8) ? 0 : 2;
            kx = ((k >> 7) & 1) ? 0 : 2;
            ci = k & 127;
        } else if (i2 < 98304) {
            const int k = ((i2 - 65536) >> 10) * 8 + j;  // 0..255
            ky = 1;
            kx = (k >> 7) ? 0 : 2;
            ci = k & 127;
        } else if (i2 < 131072) {
            const int k = ((i2 - 98304) >> 10) * 8 + j;  // 0..255
            ky = (k >> 7) ? 0 : 2;
            kx = 1;
            ci = k & 127;
        } else {
            const int k = ((i2 - 131072) >> 10) * 8 + j; // 0..127
            ky = 1; kx = 1;
            ci = k & 127;
        }
        WB[i2] = f2bf(w_up[((ci * COUT + n) * 3 + ky) * 3 + kx]);
    }
    const int i3 = idx - 221184;
    if (i3 >= 0 && i3 < 18432) {
        const int j = i3 & 7;
        const int n = (i3 >> 3) & 31;
        const int g = i3 >> 8;              // 0..71 = s*4 + kg
        const int kg = g & 3, s = g >> 2;
        const int c  = (s & 1) * 32 + kg * 8 + j;
        const int kk = s >> 1;
        const int ki = kk / 3, kj = kk - 3 * ki;
        WOF[i3] = (n < NOFF) ? f2bf(w_off[((n * CIN + c) * 3 + ki) * 3 + kj]) : (unsigned short)0;
    }
}

// ---------------- offset conv via MFMA, 1 wave per (b, h, quarter), XCD-swizzled ----------------
// Stores pixel-interleaved: offs2[b][h][w][oc], oc in [0,18)
__global__ __launch_bounds__(64, 4) void k_offset_mfma(
    const unsigned short* __restrict__ xt, const unsigned short* __restrict__ WOF,
    const float* __restrict__ b_off, float* __restrict__ offs2)
{
    const int l  = threadIdx.x;
    const int ml = l & 15;
    const int kg = l >> 4;
    // XCD swizzle: blk%8 -> XCD r; give XCD r batches {2r, 2r+1}
    const int r  = blockIdx.x & 7;
    const int i  = blockIdx.x >> 3;        // 0..511
    const int b  = 2 * r + (i >> 8);
    const int hq = i & 255;
    const int q  = hq & 3;
    const int h  = hq >> 2;
    const int w  = q * 16 + ml;
    const unsigned short* xb = xt + (size_t)b * (IH * IW * CIN);

    const f32x4 fz = {0.f, 0.f, 0.f, 0.f};
    f32x4 acc0 = fz, acc1 = fz;

    #pragma unroll
    for (int s = 0; s < 18; ++s) {
        const int kk = s >> 1;
        const int ki = kk / 3, kj = kk - 3 * ki;   // compile-time (full unroll)
        const int c0 = (s & 1) * 32 + kg * 8;
        const int yy = h - PADC + ki;
        const int xx = w - PADC + kj;
        const bf16x8 b0 = *(const bf16x8*)(WOF + (size_t)(((s * 4 + kg) * 32 + ml) * 8));
        const bf16x8 b1 = *(const bf16x8*)(WOF + (size_t)(((s * 4 + kg) * 32 + 16 + ml) * 8));
        bf16x8 a = {0, 0, 0, 0, 0, 0, 0, 0};
        if (yy >= 0 && yy < IH && xx >= 0 && xx < IW)
            a = *(const bf16x8*)(xb + (size_t)((yy * IW + xx) * CIN) + c0);
        acc0 = __builtin_amdgcn_mfma_f32_16x16x32_bf16(a, b0, acc0, 0, 0, 0);
        acc1 = __builtin_amdgcn_mfma_f32_16x16x32_bf16(a, b1, acc1, 0, 0, 0);
    }
    // D: row = kg*4 + j (pixel within quarter), col = nt*16 + ml (oc)
    #pragma unroll
    for (int nt = 0; nt < 2; ++nt) {
        const int oc = nt * 16 + ml;
        if (oc < NOFF) {
            const float bias = b_off[oc];
            const f32x4 av = nt ? acc1 : acc0;
            #pragma unroll
            for (int j = 0; j < 4; ++j) {
                const int wd = q * 16 + kg * 4 + j;
                offs2[((size_t)((b * IH + h) * IW) + wd) * NOFF + oc] = av[j] + bias;
            }
        }
    }
}

// ---------------- deformable conv via MFMA, 1 wave per (b, h, quarter), XCD-swizzled ----------------
// All 9 (dy,dx) preloaded to registers; kk loop FULLY unrolled -> compiler can
// overlap iteration k+1's corner loads with iteration k's blend+MFMA. (R11 winner)
__global__ __launch_bounds__(64, 4) void k_deform_mfma(
    const unsigned short* __restrict__ xt, const float* __restrict__ offs2,
    const unsigned short* __restrict__ WDF, const float* __restrict__ b_def,
    unsigned short* __restrict__ feats_bf)
{
    const int l  = threadIdx.x;
    const int ml = l & 15;
    const int kg = l >> 4;
    // XCD swizzle (same mapping as offset kernel)
    const int r  = blockIdx.x & 7;
    const int i  = blockIdx.x >> 3;
    const int b  = 2 * r + (i >> 8);
    const int hq = i & 255;
    const int q  = hq & 3;
    const int h  = hq >> 2;
    const int w  = q * 16 + ml;

    const unsigned short* xb = xt + (size_t)b * (IH * IW * CIN);

    // preload all 9 offset pairs (fully static indices -> registers)
    float2 dd[9];
    {
        const float* op = offs2 + ((size_t)((b * IH + h) * IW) + w) * NOFF;
        #pragma unroll
        for (int kk = 0; kk < 9; ++kk)
            dd[kk] = *(const float2*)(op + 2 * kk);
    }

    const f32x4 fz = {0.f, 0.f, 0.f, 0.f};
    f32x4 acc[8];
    #pragma unroll
    for (int nt = 0; nt < 8; ++nt) acc[nt] = fz;

    #pragma unroll
    for (int kk = 0; kk < 9; ++kk) {
        const int ki = kk / 3, kj = kk - 3 * ki;   // compile-time (full unroll)
        const float py = (float)(h - PADC + ki) + dd[kk].x;
        const float px = (float)(w - PADC + kj) + dd[kk].y;
        const float y0f = floorf(py), x0f = floorf(px);
        const float ly = py - y0f, lx = px - x0f;
        const int y0 = (int)y0f, x0 = (int)x0f;
        const float wy[2] = {1.f - ly, ly};
        const float wx[2] = {1.f - lx, lx};
        int   cidx[4];
        float cwgt[4];
        #pragma unroll
        for (int cy = 0; cy < 2; ++cy)
            #pragma unroll
            for (int cx = 0; cx < 2; ++cx) {
                const int yy = y0 + cy, xx = x0 + cx;
                const bool v = (yy >= 0) & (yy < IH) & (xx >= 0) & (xx < IW);
                cidx[cy * 2 + cx] = v ? ((yy * IW + xx) * CIN) : 0;   // branchless
                cwgt[cy * 2 + cx] = v ? (wy[cy] * wx[cx]) : 0.f;
            }
        #pragma unroll
        for (int ks = 0; ks < 2; ++ks) {
            const int c0 = ks * 32 + kg * 8;
            uint4 cv[4];
            #pragma unroll
            for (int cp = 0; cp < 4; ++cp)
                cv[cp] = *(const uint4*)(xb + cidx[cp] + c0);
            float sf[8] = {0.f, 0.f, 0.f, 0.f, 0.f, 0.f, 0.f, 0.f};
            #pragma unroll
            for (int cp = 0; cp < 4; ++cp) {
                const float wg = cwgt[cp];
                const unsigned int u0 = cv[cp].x, u1 = cv[cp].y, u2 = cv[cp].z, u3 = cv[cp].w;
                sf[0] += wg * __uint_as_float(u0 << 16);
                sf[1] += wg * __uint_as_float(u0 & 0xFFFF0000u);
                sf[2] += wg * __uint_as_float(u1 << 16);
                sf[3] += wg * __uint_as_float(u1 & 0xFFFF0000u);
                sf[4] += wg * __uint_as_float(u2 << 16);
                sf[5] += wg * __uint_as_float(u2 & 0xFFFF0000u);
                sf[6] += wg * __uint_as_float(u3 << 16);
                sf[7] += wg * __uint_as_float(u3 & 0xFFFF0000u);
            }
            union { unsigned short us[8]; bf16x8 v; } pa;
            #pragma unroll
            for (int j = 0; j < 8; ++j) pa.us[j] = f2bf(sf[j]);
            // B-fragments in two half-batches (bound transient VGPR pressure)
            #pragma unroll
            for (int half = 0; half < 2; ++half) {
                bf16x8 bfr[4];
                #pragma unroll
                for (int nn = 0; nn < 4; ++nn)
                    bfr[nn] = *(const bf16x8*)(WDF + ((size_t)((kk * 8 + ks * 4 + kg) * 128) + (half * 4 + nn) * 16 + ml) * 8);
                #pragma unroll
                for (int nn = 0; nn < 4; ++nn)
                    acc[half * 4 + nn] = __builtin_amdgcn_mfma_f32_16x16x32_bf16(pa.v, bfr[nn], acc[half * 4 + nn], 0, 0, 0);
            }
        }
    }
    // epilogue: D row = kg*4 + j (pixel), col = nt*16 + ml (channel o)
    #pragma unroll
    for (int nt = 0; nt < 8; ++nt) {
        const int o = nt * 16 + ml;
        const float bias = b_def[o];
        #pragma unroll
        for (int j = 0; j < 4; ++j) {
            const int wd = q * 16 + kg * 4 + j;
            feats_bf[((size_t)((b * IH + h) * IW) + wd) * COUT + o] = f2bf(acc[nt][j] + bias);
        }
    }
}

// ---------------- convT via MFMA: paired oy rows, slab-free epilogue, XCD-swizzled ----------------
__global__ __launch_bounds__(256) void k_convT_mfma(
    const unsigned short* __restrict__ feats_bf, const unsigned short* __restrict__ WB,
    unsigned short* __restrict__ y_bf, float* __restrict__ partials)
{
    __shared__ __align__(16) char smem[33792];   // 2 slots x 16896

    const int tid = threadIdx.x;
    const int l   = tid & 63;
    const int wv  = tid >> 6;
    const int ml  = l & 15;
    const int kg  = l >> 4;
    const int blk = blockIdx.x;
    // XCD swizzle: 1040 = 8 XCDs x 130; XCD r gets batches {2r, 2r+1}
    const int r_  = blk & 7;
    const int i_  = blk >> 3;              // 0..129
    const int b   = 2 * r_ + (i_ >= 65 ? 1 : 0);
    const int t   = (i_ >= 65) ? (i_ - 65) : i_;

    for (int r = 0; r < 2; ++r) {
        char* dstbase = smem + r * 16896;
        const int iy = t - 1 + r;
        if (iy < 0 || iy > 63) {
            for (int i = tid; i < 1056; i += 256)
                *(uint4*)(dstbase + i * 16) = uint4{0, 0, 0, 0};
        } else {
            const unsigned short* src = feats_bf + (size_t)(b * IH + iy) * (IW * COUT);
            for (int i = tid; i < 1024; i += 256) {
                const uint4 v = *(const uint4*)(src + i * 8);
                const int G = 16 + i;
                const int phys = G ^ ((G >> 4) & 7);
                *(uint4*)(dstbase + phys * 16) = v;
            }
            if (tid < 32) {
                const int G = (tid < 16) ? tid : (1024 + tid);
                const int phys = G ^ ((G >> 4) & 7);
                *(uint4*)(dstbase + phys * 16) = uint4{0, 0, 0, 0};
            }
        }
    }
    __syncthreads();

    const int n0 = wv * 32;
    const f32x4 fz = {0.f, 0.f, 0.f, 0.f};
    float sacc[2] = {0.f, 0.f}, qacc[2] = {0.f, 0.f};

    #pragma unroll 1
    for (int p = 0; p < 2; ++p) {                 // p=0: oy=2t, p=1: oy=2t+1
        if (p == 1 && t == 64) break;
        const int oy = 2 * t + p;
        const unsigned short* segG0 = WB + (p ? 65536 : 0);
        const unsigned short* segG1 = WB + (p ? 131072 : 98304);
        const int nK0 = p ? 8 : 16;
        const int nK1 = p ? 4 : 8;

        f32x4 acc0[5][2], acc1[4][2];
        #pragma unroll
        for (int m = 0; m < 5; ++m) { acc0[m][0] = fz; acc0[m][1] = fz; }
        #pragma unroll
        for (int m = 0; m < 4; ++m) { acc1[m][0] = fz; acc1[m][1] = fz; }

        for (int ks = 0; ks < nK0; ++ks) {
            const int kk   = ks * 32 + kg * 8;
            const int slot = p ? 1 : (kk >> 8);
            const int kb   = (kk & 255) >> 3;
            const bf16x8 b0 = *(const bf16x8*)(segG0 + ((ks * 4 + kg) * 128 + n0 + ml) * 8);
            const bf16x8 b1 = *(const bf16x8*)(segG0 + ((ks * 4 + kg) * 128 + n0 + 16 + ml) * 8);
            #pragma unroll
            for (int mt = 0; mt < 5; ++mt) {
                int tx = mt * 16 + ml; if (tx > 64) tx = 64;
                const int G = tx * 16 + kb;
                const int phys = G ^ ((G >> 4) & 7);
                const bf16x8 a = *(const bf16x8*)(smem + slot * 16896 + phys * 16);
                acc0[mt][0] = __builtin_amdgcn_mfma_f32_16x16x32_bf16(a, b0, acc0[mt][0], 0, 0, 0);
                acc0[mt][1] = __builtin_amdgcn_mfma_f32_16x16x32_bf16(a, b1, acc0[mt][1], 0, 0, 0);
            }
        }
        for (int ks = 0; ks < nK1; ++ks) {
            const int kk   = ks * 32 + kg * 8;
            const int slot = p ? 1 : (kk >> 7);
            const int kb   = (kk & 127) >> 3;
            const bf16x8 b0 = *(const bf16x8*)(segG1 + ((ks * 4 + kg) * 128 + n0 + ml) * 8);
            const bf16x8 b1 = *(const bf16x8*)(segG1 + ((ks * 4 + kg) * 128 + n0 + 16 + ml) * 8);
            #pragma unroll
            for (int mt = 0; mt < 4; ++mt) {
                const int tx = mt * 16 + ml;
                const int G = 16 + tx * 16 + kb;
                const int phys = G ^ ((G >> 4) & 7);
                const bf16x8 a = *(const bf16x8*)(smem + slot * 16896 + phys * 16);
                acc1[mt][0] = __builtin_amdgcn_mfma_f32_16x16x32_bf16(a, b0, acc1[mt][0], 0, 0, 0);
                acc1[mt][1] = __builtin_amdgcn_mfma_f32_16x16x32_bf16(a, b1, acc1[mt][1], 0, 0, 0);
            }
        }

        #pragma unroll
        for (int nt = 0; nt < 2; ++nt) {
            const int co = n0 + nt * 16 + ml;
            unsigned int* drow32 = (unsigned int*)(y_bf + ((size_t)(b * COUT + co) * OYX + oy) * OXP);
            #pragma unroll
            for (int mt = 0; mt < 4; ++mt) {
                unsigned int pk[4];
                #pragma unroll
                for (int j = 0; j < 4; ++j) {
                    const float ve = acc0[mt][nt][j];
                    const float vo = acc1[mt][nt][j];
                    pk[j] = (unsigned int)f2bf(ve) | ((unsigned int)f2bf(vo) << 16);
                    sacc[nt] += ve + vo;
                    qacc[nt] += ve * ve + vo * vo;
                }
                *(uint4*)(drow32 + mt * 16 + kg * 4) = uint4{pk[0], pk[1], pk[2], pk[3]};
            }
            if (kg == 0) {
                const float ve = acc0[4][nt][0];
                drow32[64] = (unsigned int)f2bf(ve);
                sacc[nt] += ve;
                qacc[nt] += ve * ve;
            }
        }
    }

    #pragma unroll
    for (int nt = 0; nt < 2; ++nt) {
        float ss = sacc[nt], qq = qacc[nt];
        ss += __shfl_xor(ss, 16, 64); qq += __shfl_xor(qq, 16, 64);
        ss += __shfl_xor(ss, 32, 64); qq += __shfl_xor(qq, 32, 64);
        if (kg == 0) {
            float* pp = partials + ((size_t)blk * COUT + n0 + nt * 16 + ml) * 2;
            pp[0] = ss; pp[1] = qq;
        }
    }
}

// ---------------- BN finalize: reduce per-block partials ----------------
__global__ __launch_bounds__(256) void k_bn_final(const float* __restrict__ partials,
                                                  float* __restrict__ stats)
{
    const int c = blockIdx.x;      // 128
    const int tid = threadIdx.x;
    float s = 0.f, q = 0.f;
    for (int i = tid; i < NBLK_CT; i += 256) {
        const float* pp = partials + ((size_t)i * COUT + c) * 2;
        s += pp[0]; q += pp[1];
    }
    __shared__ float rs[256], rq[256];
    rs[tid] = s; rq[tid] = q;
    __syncthreads();
    for (int off = 128; off > 0; off >>= 1) {
        if (tid < off) { rs[tid] += rs[tid + off]; rq[tid] += rq[tid + off]; }
        __syncthreads();
    }
    if (tid == 0) {
        const float n = (float)(NB * SPO);
        const float mean = rs[0] / n;
        const float var  = rq[0] / n - mean * mean;
        stats[c] = mean;
        stats[COUT + c] = rsqrtf(var + BNEPS);
    }
}

// ---------------- BN apply + ReLU: 8-wide bf16 read (padded rows), f32 write ----------------
__global__ __launch_bounds__(256) void k_bn_apply(
    const unsigned short* __restrict__ y_bf, float* __restrict__ y,
    const float* __restrict__ stats,
    const float* __restrict__ gamma, const float* __restrict__ beta)
{
    const int v = blockIdx.x * 256 + threadIdx.x;   // exact: 264192*17 = 4,491,264
    const int rid = v / 17;
    const int c   = v - rid * 17;
    const int co  = (rid / OYX) & (COUT - 1);
    const float mean = stats[co], rstd = stats[COUT + co];
    const float ga = gamma[co], be = beta[co];
    const int ox0 = c * 8;

    const uint4 u = *(const uint4*)(y_bf + (size_t)rid * OXP + ox0);
    const unsigned int uu[4] = {u.x, u.y, u.z, u.w};
    float* dst = y + (size_t)rid * OYX + ox0;
    const int nv = (c < 16) ? 8 : 1;
    #pragma unroll
    for (int m = 0; m < 4; ++m) {
        float v0 = bf2f((unsigned short)(uu[m] & 0xFFFFu));
        float v1 = bf2f((unsigned short)(uu[m] >> 16));
        v0 = fmaxf((v0 - mean) * rstd * ga + be, 0.f);
        v1 = fmaxf((v1 - mean) * rstd * ga + be, 0.f);
        if (2 * m < nv)     dst[2 * m]     = v0;
        if (2 * m + 1 < nv) dst[2 * m + 1] = v1;
    }
}

extern "C" void kernel_launch(void* const* d_in, const int* in_sizes, int n_in,
                              void* d_out, int out_size, void* d_ws, size_t ws_size,
                              hipStream_t stream)
{
    const float* x     = (const float*)d_in[0];
    const float* w_off = (const float*)d_in[1];
    const float* b_off = (const float*)d_in[2];
    const float* w_def = (const float*)d_in[3];
    const float* b_def = (const float*)d_in[4];
    const float* w_up  = (const float*)d_in[5];
    const float* b_up  = (const float*)d_in[6];  (void)b_up;  // cancels in BN
    const float* gamma = (const float*)d_in[7];
    const float* beta  = (const float*)d_in[8];
    float* y = (float*)d_out;

    float* ws       = (float*)d_ws;
    float* stats    = ws;                     //       256 f32
    float* partials = stats + 256;            //   266,240 f32 (1040*128*2)
    float* offs2    = partials + 528384;      // 1,179,648 f32 ([b][h][w][18])
    unsigned short* xt       = (unsigned short*)(offs2 + 1179648);    //  4,194,304 bf16
    unsigned short* WDF      = xt + 4194304;                          //     73,728 bf16
    unsigned short* feats_bf = WDF + 73728;                           //  8,388,608 bf16
    unsigned short* WB       = feats_bf + 8388608;                    //    147,456 bf16
    unsigned short* WOF      = WB + 147456;                           //     18,432 bf16
    unsigned short* y_bf     = WOF + 18432;                           // 35,930,112 bf16 (padded rows)

    k_pre          <<<dim3(1960),   dim3(256), 0, stream>>>(x, w_def, w_up, w_off, xt, WDF, WB, WOF);
    k_offset_mfma  <<<dim3(4096),   dim3(64),  0, stream>>>(xt, WOF, b_off, offs2);
    k_deform_mfma  <<<dim3(4096),   dim3(64),  0, stream>>>(xt, offs2, WDF, b_def, feats_bf);
    k_convT_mfma   <<<dim3(NBLK_CT),dim3(256), 0, stream>>>(feats_bf, WB, y_bf, partials);
    k_bn_final     <<<dim3(128),    dim3(256), 0, stream>>>(partials, stats);
    k_bn_apply     <<<dim3(17544),  dim3(256), 0, stream>>>(y_bf, y, stats, gamma, beta);
}